// Round 3
// baseline (106.090 us; speedup 1.0000x reference)
//
#include <hip/hip_runtime.h>
#include <math.h>

#define HDIM 1024
#define VDIM 50257
#define LDIM 512

// ws float offsets
#define WS_ATTLOG 0      // [0,512)     attention logits
#define WS_CTX    512    // [512,1536)  attn_applied (atomic accum)
#define WS_X      1536   // [1536,2560) GRU input x
#define WS_GH     2560   // [2560,5632) gh = h@W_hh.T + b_hh
#define WS_BUCK   5632   // [5632,5696) 64 exp-sum buckets
#define WS_HNEW   5696   // [5696,6720) h_new (16B-aligned)

__device__ __forceinline__ float waveSum(float v) {
#pragma unroll
    for (int o = 32; o; o >>= 1) v += __shfl_down(v, o, 64);
    return v;
}

// K1: attn logits (blocks 0..127, 4 rows each) + gh rows (blocks 128..895)
//     + zero the atomic accumulators (block 0).
__global__ __launch_bounds__(256) void k1(const int* __restrict__ idx_p,
                                          const float* __restrict__ hidden,
                                          const float* __restrict__ emb,
                                          const float* __restrict__ attn_W,
                                          const float* __restrict__ attn_b,
                                          const float* __restrict__ W_hh,
                                          const float* __restrict__ b_hh,
                                          float* __restrict__ ws) {
    const int blk = blockIdx.x, t = threadIdx.x;
    const int wid = t >> 6, lane = t & 63;
    if (blk == 0) {
        ws[WS_CTX + t] = 0.f; ws[WS_CTX + 256 + t] = 0.f;
        ws[WS_CTX + 512 + t] = 0.f; ws[WS_CTX + 768 + t] = 0.f;
        if (t < 64) ws[WS_BUCK + t] = 0.f;
    }
    const float4* h4 = (const float4*)hidden;
    if (blk < 128) {
        const float4* e4 = (const float4*)(emb + (size_t)idx_p[0] * HDIM);
        int row = blk * 4 + wid;                        // 0..511
        const float4* w4 = (const float4*)(attn_W + (size_t)row * 2 * HDIM);
        float acc = 0.f;
#pragma unroll
        for (int k = 0; k < 8; ++k) {
            int c = lane + 64 * k;                      // float4 chunk 0..511
            float4 w = w4[c];
            float4 x = (c < 256) ? e4[c] : h4[c - 256];
            acc += w.x * x.x + w.y * x.y + w.z * x.z + w.w * x.w;
        }
        acc = waveSum(acc);
        if (lane == 0) ws[WS_ATTLOG + row] = acc + attn_b[row];
    } else {
        int k = (blk - 128) * 4 + wid;                  // 0..3071
        const float4* w4 = (const float4*)(W_hh + (size_t)k * HDIM);
        float acc = 0.f;
#pragma unroll
        for (int q = 0; q < 4; ++q) {
            int c = lane + 64 * q;
            float4 w = w4[c]; float4 x = h4[c];
            acc += w.x * x.x + w.y * x.y + w.z * x.z + w.w * x.w;
        }
        acc = waveSum(acc);
        if (lane == 0) ws[WS_GH + k] = acc + b_hh[k];
    }
}

// K2: softmax(512) computed redundantly per block in LDS, then
//     blocks 0..63: context slice (atomicAdd); block 64: attn-weight output.
__global__ __launch_bounds__(256) void k2(const float* __restrict__ enc,
                                          float* __restrict__ ws,
                                          float* __restrict__ out) {
    __shared__ float sred[4];
    __shared__ float sW[512];
    const int blk = blockIdx.x, t = threadIdx.x;
    const int wid = t >> 6, lane = t & 63;
    float v0 = ws[WS_ATTLOG + t], v1 = ws[WS_ATTLOG + 256 + t];
    float m = fmaxf(v0, v1);
#pragma unroll
    for (int o = 32; o; o >>= 1) m = fmaxf(m, __shfl_down(m, o, 64));
    if (lane == 0) sred[wid] = m;
    __syncthreads();
    m = fmaxf(fmaxf(sred[0], sred[1]), fmaxf(sred[2], sred[3]));
    __syncthreads();
    float e0 = expf(v0 - m), e1 = expf(v1 - m);
    float s = waveSum(e0 + e1);
    if (lane == 0) sred[wid] = s;
    __syncthreads();
    s = sred[0] + sred[1] + sred[2] + sred[3];
    float inv = 1.f / s;
    sW[t] = e0 * inv; sW[256 + t] = e1 * inv;
    __syncthreads();
    if (blk == 64) {
        out[VDIM + HDIM + t] = sW[t];
        out[VDIM + HDIM + 256 + t] = sW[256 + t];
    } else {
        int lc = blk & 15, hb = blk >> 4;
        int h = hb * 256 + t;
        int l0 = lc * 32;
        float acc = 0.f;
#pragma unroll 8
        for (int j = 0; j < 32; ++j)
            acc += sW[l0 + j] * enc[(size_t)(l0 + j) * HDIM + h];
        atomicAdd(&ws[WS_CTX + h], acc);
    }
}

// K3: x[j] = relu(dot(cat(emb_row, ctx), comb_W[j]) + comb_b[j])
__global__ __launch_bounds__(256) void k3(const int* __restrict__ idx_p,
                                          const float* __restrict__ emb,
                                          const float* __restrict__ comb_W,
                                          const float* __restrict__ comb_b,
                                          float* __restrict__ ws) {
    const int t = threadIdx.x, wid = t >> 6, lane = t & 63;
    int j = blockIdx.x * 4 + wid;                       // 0..1023
    const float4* w4 = (const float4*)(comb_W + (size_t)j * 2 * HDIM);
    const float4* e4 = (const float4*)(emb + (size_t)idx_p[0] * HDIM);
    const float4* c4 = (const float4*)(ws + WS_CTX);
    float acc = 0.f;
#pragma unroll
    for (int k = 0; k < 8; ++k) {
        int c = lane + 64 * k;
        float4 w = w4[c];
        float4 x = (c < 256) ? e4[c] : c4[c - 256];
        acc += w.x * x.x + w.y * x.y + w.z * x.z + w.w * x.w;
    }
    acc = waveSum(acc);
    if (lane == 0) ws[WS_X + j] = fmaxf(acc + comb_b[j], 0.f);
}

// K4: fused gi + GRU gate. One wave per h-index: 3 W_ih row-dots, then gate.
__global__ __launch_bounds__(256) void k4(const float* __restrict__ hidden,
                                          const float* __restrict__ W_ih,
                                          const float* __restrict__ b_ih,
                                          float* __restrict__ ws,
                                          float* __restrict__ out) {
    const int t = threadIdx.x, wid = t >> 6, lane = t & 63;
    int i = blockIdx.x * 4 + wid;                       // h index 0..1023
    const float4* x4 = (const float4*)(ws + WS_X);
    float a[3];
#pragma unroll
    for (int r = 0; r < 3; ++r) {
        const float4* w4 = (const float4*)(W_ih + (size_t)(r * HDIM + i) * HDIM);
        float acc = 0.f;
#pragma unroll
        for (int q = 0; q < 4; ++q) {
            int c = lane + 64 * q;
            float4 w = w4[c]; float4 x = x4[c];
            acc += w.x * x.x + w.y * x.y + w.z * x.z + w.w * x.w;
        }
        a[r] = waveSum(acc);
    }
    if (lane == 0) {
        float gi_r = a[0] + b_ih[i];
        float gi_z = a[1] + b_ih[HDIM + i];
        float gi_n = a[2] + b_ih[2 * HDIM + i];
        float gh_r = ws[WS_GH + i];
        float gh_z = ws[WS_GH + HDIM + i];
        float gh_n = ws[WS_GH + 2 * HDIM + i];
        float r_ = 1.f / (1.f + expf(-(gi_r + gh_r)));
        float z  = 1.f / (1.f + expf(-(gi_z + gh_z)));
        float n  = tanhf(gi_n + r_ * gh_n);
        float hn = (1.f - z) * n + z * hidden[i];
        ws[WS_HNEW + i] = hn;
        out[VDIM + i]   = hn;
    }
}

// K5: logits + per-block exp partials into 64 buckets.
__global__ __launch_bounds__(256) void k5(const float* __restrict__ out_W,
                                          const float* __restrict__ out_b,
                                          float* __restrict__ ws,
                                          float* __restrict__ out) {
    __shared__ float se[4];
    const int t = threadIdx.x, wid = t >> 6, lane = t & 63;
    int v = blockIdx.x * 4 + wid;
    const float4* h4 = (const float4*)(ws + WS_HNEW);
    if (v < VDIM) {
        const float4* w4 = (const float4*)(out_W + (size_t)v * HDIM);
        float acc = 0.f;
#pragma unroll
        for (int q = 0; q < 4; ++q) {
            int c = lane + 64 * q;
            float4 w = w4[c]; float4 x = h4[c];
            acc += w.x * x.x + w.y * x.y + w.z * x.z + w.w * x.w;
        }
        acc = waveSum(acc);
        if (lane == 0) {
            float logit = acc + out_b[v];
            out[v] = logit;
            se[wid] = expf(logit);
        }
    } else if (lane == 0) {
        se[wid] = 0.f;
    }
    __syncthreads();
    if (t == 0)
        atomicAdd(&ws[WS_BUCK + (blockIdx.x & 63)], se[0] + se[1] + se[2] + se[3]);
}

// K6: out[i] -= log(sum of buckets)
__global__ __launch_bounds__(256) void k6(const float* __restrict__ ws,
                                          float* __restrict__ out) {
    __shared__ float s_ls;
    const int t = threadIdx.x;
    if (t < 64) {
        float b = waveSum(ws[WS_BUCK + t]);
        if (t == 0) s_ls = logf(b);
    }
    __syncthreads();
    int i = blockIdx.x * 256 + t;
    if (i < VDIM) out[i] -= s_ls;
}

extern "C" void kernel_launch(void* const* d_in, const int* in_sizes, int n_in,
                              void* d_out, int out_size, void* d_ws, size_t ws_size,
                              hipStream_t stream) {
    const int*   idx    = (const int*)d_in[0];
    const float* hidden = (const float*)d_in[1];
    const float* enc    = (const float*)d_in[2];
    const float* emb    = (const float*)d_in[3];
    const float* attn_W = (const float*)d_in[4];
    const float* attn_b = (const float*)d_in[5];
    const float* comb_W = (const float*)d_in[6];
    const float* comb_b = (const float*)d_in[7];
    const float* W_ih   = (const float*)d_in[8];
    const float* W_hh   = (const float*)d_in[9];
    const float* b_ih   = (const float*)d_in[10];
    const float* b_hh   = (const float*)d_in[11];
    const float* out_W  = (const float*)d_in[12];
    const float* out_b  = (const float*)d_in[13];

    float* out = (float*)d_out;                 // [V logits][H h_new][L attn_w]
    float* ws  = (float*)d_ws;

    k1<<<896, 256, 0, stream>>>(idx, hidden, emb, attn_W, attn_b, W_hh, b_hh, ws);
    k2<<<65, 256, 0, stream>>>(enc, ws, out);
    k3<<<256, 256, 0, stream>>>(idx, emb, comb_W, comb_b, ws);
    k4<<<256, 256, 0, stream>>>(hidden, W_ih, b_ih, ws, out);
    k5<<<(VDIM + 3) / 4, 256, 0, stream>>>(out_W, out_b, ws, out);
    k6<<<(VDIM + 255) / 256, 256, 0, stream>>>(ws, out);
}